// Round 18
// baseline (136.111 us; speedup 1.0000x reference)
//
#include <hip/hip_runtime.h>
#include <hip/hip_bf16.h>
#include <stdint.h>

#define BATCH 2
#define SEQ 2048
#define DMODEL 1024
#define NHEADS 16
#define HDIM 64
#define MROWS (BATCH*SEQ)   /* 4096 */
#define N3 (3*DMODEL)       /* 3072 */

typedef __attribute__((ext_vector_type(8))) __bf16 bf16x8;
typedef __attribute__((ext_vector_type(4))) float f32x4;

__device__ __forceinline__ ushort f2b(float f) {
  uint32_t u = __builtin_bit_cast(uint32_t, f);
  uint32_t r = (u + 0x7FFFu + ((u >> 16) & 1u)) >> 16;
  return (ushort)r;
}
__device__ __forceinline__ float b2f(ushort h) {
  return __builtin_bit_cast(float, (uint32_t)h << 16);
}
__device__ __forceinline__ float exp2_hw(float x) {
  float r;
  asm("v_exp_f32 %0, %1" : "=v"(r) : "v"(x));
  return r;
}
/* v_cvt_pk_bf16_f32: d.lo = bf16_rne(a), d.hi = bf16_rne(b) */
__device__ __forceinline__ uint32_t cvtpk(float a, float b) {
  uint32_t r;
  asm("v_cvt_pk_bf16_f32 %0, %1, %2" : "=v"(r) : "v"(a), "v"(b));
  return r;
}

/* ---------------- fused f32 -> bf16 convert for x, W_kqv, W_o (one launch) ---------------- */
__global__ void f2b3_kernel(const float* __restrict__ a, const float* __restrict__ b,
                            const float* __restrict__ c,
                            ushort* __restrict__ oa, ushort* __restrict__ ob,
                            ushort* __restrict__ oc, int na, int nb, int nc) {
  int i = blockIdx.x * blockDim.x + threadIdx.x;
  const float* src; ushort* dst; int off;
  if (i < na)           { src = a; dst = oa; off = i; }
  else if (i < na + nb) { src = b; dst = ob; off = i - na; }
  else if (i < na + nb + nc) { src = c; dst = oc; off = i - na - nb; }
  else return;
  float4 v = ((const float4*)src)[off];
  uint32_t lo = cvtpk(v.x, v.y), hi_ = cvtpk(v.z, v.w);
  ((uint2*)dst)[off] = make_uint2(lo, hi_);
}

/* ---------------- NT GEMM 128^2, BK=64, involution swizzle + counted-vmcnt pipeline ----------------
   Tile economics of R16's verified 128x128/BK=64/swizzle kernel, with the barrier-drain
   removed using the R17-verified gemm256 skeleton (ported 1:1 — same per-wave FIFO
   constants: A/B stage = 4 loads/wave, boundary wait = vmcnt(4)):
     top: STAGE_A(t+1) -> wait vmcnt(4) [tile t landed, A(t+1) in flight] -> barrier
     kk=0 MFMAs -> STAGE_B(t+1) -> mid barrier -> kk=1 MFMAs -> end barrier.
   WAR: stages target the non-read buffer; its readers finished before the end-of-iter
   barrier that precedes issue. LDS 2x32KB = 64KB -> 2 blocks/CU (fixes gemm256's
   1-block/CU occupancy loss). */
template<int OUTF>
__global__ __launch_bounds__(256)
void gemm_bt(const ushort* __restrict__ A, const ushort* __restrict__ Bw,
             void* __restrict__ Cv, int M, int N, int K) {
  __shared__ __align__(16) ushort As[2][128*64];
  __shared__ __align__(16) ushort Bs[2][128*64];
  const int tid  = threadIdx.x;
  const int wid  = tid >> 6;
  const int lane = tid & 63;
  const int wr   = wid >> 1, wc = wid & 1;
  const int l16  = lane & 15, lhi = lane >> 4;
  const int nb   = N >> 7;
  const int brow = (blockIdx.x / nb) << 7;
  const int bcol = (blockIdx.x % nb) << 7;
  const int sw   = l16 & 7;
  const int nt   = K >> 6;

  f32x4 acc[4][4] = {};

  auto STAGE_A = [&](int buf, int t) {
#pragma unroll
    for (int j = 0; j < 4; ++j) {
      const int cb  = (wid * 4 + j) * 64;
      const int ci  = cb + lane;
      const int row = ci >> 3;
      const int sl  = (ci & 7) ^ (row & 7);
      __builtin_amdgcn_global_load_lds(
          (const __attribute__((address_space(1))) void*)(A + (size_t)(brow + row) * K + t * 64 + sl * 8),
          (__attribute__((address_space(3))) void*)(&As[buf][0] + cb * 8), 16, 0, 0);
    }
  };
  auto STAGE_B = [&](int buf, int t) {
#pragma unroll
    for (int j = 0; j < 4; ++j) {
      const int cb  = (wid * 4 + j) * 64;
      const int ci  = cb + lane;
      const int row = ci >> 3;
      const int sl  = (ci & 7) ^ (row & 7);
      __builtin_amdgcn_global_load_lds(
          (const __attribute__((address_space(1))) void*)(Bw + (size_t)(bcol + row) * K + t * 64 + sl * 8),
          (__attribute__((address_space(3))) void*)(&Bs[buf][0] + cb * 8), 16, 0, 0);
    }
  };

  STAGE_A(0, 0);
  STAGE_B(0, 0);

  for (int t = 0; t < nt; ++t) {
    const int cur = t & 1;
    const int nxt = cur ^ 1;
    if (t + 1 < nt) {
      STAGE_A(nxt, t + 1);
      asm volatile("s_waitcnt vmcnt(4)" ::: "memory");
    } else {
      asm volatile("s_waitcnt vmcnt(0)" ::: "memory");
    }
    __builtin_amdgcn_s_barrier();
    __builtin_amdgcn_sched_barrier(0);

    const ushort* as_ = &As[cur][0];
    const ushort* bs_ = &Bs[cur][0];

    bf16x8 af[4], bfr[4];
    /* ---- kk = 0 ---- */
#pragma unroll
    for (int m = 0; m < 4; ++m)
      af[m] = *(const bf16x8*)(as_ + (wr*64 + m*16 + l16)*64 + ((lhi ^ sw) * 8));
#pragma unroll
    for (int n = 0; n < 4; ++n)
      bfr[n] = *(const bf16x8*)(bs_ + (wc*64 + n*16 + l16)*64 + ((lhi ^ sw) * 8));
    __builtin_amdgcn_s_setprio(1);
#pragma unroll
    for (int m = 0; m < 4; ++m)
#pragma unroll
      for (int n = 0; n < 4; ++n)
        acc[m][n] = __builtin_amdgcn_mfma_f32_16x16x32_bf16(af[m], bfr[n], acc[m][n], 0, 0, 0);
    __builtin_amdgcn_s_setprio(0);

    if (t + 1 < nt) STAGE_B(nxt, t + 1);
    __builtin_amdgcn_s_barrier();       /* mid phase-lock */
    __builtin_amdgcn_sched_barrier(0);

    /* ---- kk = 1 ---- */
#pragma unroll
    for (int m = 0; m < 4; ++m)
      af[m] = *(const bf16x8*)(as_ + (wr*64 + m*16 + l16)*64 + (((4+lhi) ^ sw) * 8));
#pragma unroll
    for (int n = 0; n < 4; ++n)
      bfr[n] = *(const bf16x8*)(bs_ + (wc*64 + n*16 + l16)*64 + (((4+lhi) ^ sw) * 8));
    __builtin_amdgcn_s_setprio(1);
#pragma unroll
    for (int m = 0; m < 4; ++m)
#pragma unroll
      for (int n = 0; n < 4; ++n)
        acc[m][n] = __builtin_amdgcn_mfma_f32_16x16x32_bf16(af[m], bfr[n], acc[m][n], 0, 0, 0);
    __builtin_amdgcn_s_setprio(0);

    __builtin_amdgcn_s_barrier();       /* end-of-iteration: reads of buf[cur] done */
    __builtin_amdgcn_sched_barrier(0);
  }

#pragma unroll
  for (int m = 0; m < 4; ++m)
#pragma unroll
    for (int n = 0; n < 4; ++n)
#pragma unroll
      for (int r = 0; r < 4; ++r) {
        const int row = brow + wr*64 + m*16 + lhi*4 + r;
        const int col = bcol + wc*64 + n*16 + l16;
        if (OUTF) ((float*)Cv)[(size_t)row * N + col] = acc[m][n][r];
        else      ((ushort*)Cv)[(size_t)row * N + col] = f2b(acc[m][n][r]);
      }
}

/* ---------------- prep: fused V-transpose (blocks 0..1023) + RoPE (blocks 1024..9215) ---------------- */
__global__ __launch_bounds__(256)
void prep_kernel(const ushort* __restrict__ kqv,
                 ushort* __restrict__ qb, ushort* __restrict__ kb, ushort* __restrict__ vt) {
  __shared__ ushort tile[64][65];
  if (blockIdx.x < 1024) {
    int bid = blockIdx.x;
    int lt = bid & 31, bh = bid >> 5;
    int b = bh >> 4, h = bh & 15;
    int tid = threadIdx.x;
    int r = tid >> 2, cq = tid & 3;
    size_t gbase = ((size_t)(b * SEQ + lt * 64 + r)) * N3 + 2 * DMODEL + h * HDIM + cq * 16;
#pragma unroll
    for (int j = 0; j < 16; ++j) tile[r][cq * 16 + j] = kqv[gbase + j];
    __syncthreads();
    int d = tid >> 2;
    size_t obase = ((size_t)(bh * HDIM + d)) * SEQ + lt * 64 + cq * 16;
#pragma unroll
    for (int j = 0; j < 16; ++j) vt[obase + j] = tile[cq * 16 + j][d];
  } else {
    const float SC = 0.18033688011112042f;  /* 0.125 * log2(e) */
    int idx = (blockIdx.x - 1024) * 256 + threadIdx.x;
    int i  = idx & 31;
    int h  = (idx >> 5) & 15;
    int bl = idx >> 9;
    int l  = bl & (SEQ - 1);
    int b  = bl >> 11;
    float inv = exp2f((float)i * -0.4152410118609203f);  /* 10000^(-i/32) */
    float ang = (float)l * inv;
    float s, c;
    sincosf(ang, &s, &c);
    size_t base = (size_t)bl * N3 + h * HDIM + 2 * i;
    uint32_t kp = *(const uint32_t*)(kqv + base);
    uint32_t qp = *(const uint32_t*)(kqv + base + DMODEL);
    float k1 = b2f((ushort)(kp & 0xffff)), k2 = b2f((ushort)(kp >> 16));
    float q1 = b2f((ushort)(qp & 0xffff)), q2 = b2f((ushort)(qp >> 16));
    float kr1 = k1 * c - k2 * s, kr2 = k1 * s + k2 * c;
    float qr1 = (q1 * c - q2 * s) * SC, qr2 = (q1 * s + q2 * c) * SC;
    size_t ob = ((size_t)(b * NHEADS + h) * SEQ + l) * HDIM + 2 * i;
    *(uint32_t*)(kb + ob) = cvtpk(kr1, kr2);
    *(uint32_t*)(qb + ob) = cvtpk(qr1, qr2);
  }
}

/* ---------------- Flash attention (R10 verified, 45.6us): folded pair, counted-vmcnt ---------------- */
__global__ __launch_bounds__(256, 2)
void attn_kernel(const ushort* __restrict__ qb, const ushort* __restrict__ kb,
                 const ushort* __restrict__ vt, ushort* __restrict__ ao) {
  __shared__ __align__(16) ushort Kbuf[3][4096];   /* [kv 64][d 64] swizzled */
  __shared__ __align__(16) ushort Vbuf[3][4096];   /* [d 64][kv 64] swizzled */
  __shared__ __align__(16) ushort plds[4][1024];   /* per-wave P bounce */
  const int bid = blockIdx.x;
  const int bh = bid & 31;
  const int p  = bid >> 5;           /* 0..15 */
  const int qtA = p, qtB = 31 - p;   /* qtB >= qtA >= 0; qtB >= 16 */

  const int wid = threadIdx.x >> 6, lane = threadIdx.x & 63;
  const int l16 = lane & 15, lhi = lane >> 4;
  const int r0A = qtA * 64 + wid * 16;
  const int r0B = qtB * 64 + wid * 16;

  const ushort* Q  = qb + (size_t)bh * SEQ * HDIM;
  const ushort* Kp = kb + (size_t)bh * SEQ * HDIM;
  const ushort* Vp = vt + (size_t)bh * HDIM * SEQ;

  bf16x8 qfA[2], qfB[2];
#pragma unroll
  for (int kc = 0; kc < 2; ++kc) {
    qfA[kc] = *(const bf16x8*)(Q + (size_t)(r0A + l16) * HDIM + kc * 32 + lhi * 8);
    qfB[kc] = *(const bf16x8*)(Q + (size_t)(r0B + l16) * HDIM + kc * 32 + lhi * 8);
  }

  float mqA = -3.0e38f, lsA = 0.0f, mqB = -3.0e38f, lsB = 0.0f;
  f32x4 oA[4] = {}, oB[4] = {};

  char* pbase = (char*)&plds[wid][0];
  const int swz = (l16 & 7) << 4;

  auto STAGE = [&](int buf, int kt) {
    ushort* kd = &Kbuf[buf][0];
    ushort* vd = &Vbuf[buf][0];
    const ushort* kg = Kp + (size_t)kt * 64 * HDIM;
    const ushort* vg = Vp + kt * 64;
#pragma unroll
    for (int it = 0; it < 2; ++it) {
      const int cb = it * 256 + wid * 64;
      const int ci = cb + lane;
      const int row = ci >> 3;
      const int sl  = (ci & 7) ^ (row & 7);
      __builtin_amdgcn_global_load_lds(
          (const __attribute__((address_space(1))) void*)(kg + row * HDIM + sl * 8),
          (__attribute__((address_space(3))) void*)(kd + cb * 8), 16, 0, 0);
      __builtin_amdgcn_global_load_lds(
          (const __attribute__((address_space(1))) void*)(vg + (size_t)row * SEQ + sl * 8),
          (__attribute__((address_space(3))) void*)(vd + cb * 8), 16, 0, 0);
    }
  };

  auto BODY = [&](const char* kc_, const char* vc_, bf16x8 (&qf)[2],
                  float& mq, float& lsq, f32x4 (&o)[4], int r0, int qt, int kt) {
    f32x4 s[4];
#pragma unroll
    for (int n = 0; n < 4; ++n) {
      const int kvr = n * 16 + l16;
      bf16x8 kf0 = *(const bf16x8*)(kc_ + kvr*128 + ((lhi     ^ (kvr&7)) * 16));
      bf16x8 kf1 = *(const bf16x8*)(kc_ + kvr*128 + (((4+lhi) ^ (kvr&7)) * 16));
      f32x4 z = 0.0f;
      z = __builtin_amdgcn_mfma_f32_16x16x32_bf16(kf0, qf[0], z, 0, 0, 0);
      z = __builtin_amdgcn_mfma_f32_16x16x32_bf16(kf1, qf[1], z, 0, 0, 0);
      s[n] = z;
    }
    if (kt == qt) {
#pragma unroll
      for (int n = 0; n < 4; ++n)
#pragma unroll
        for (int r = 0; r < 4; ++r)
          if (kt*64 + n*16 + lhi*4 + r > r0 + l16) s[n][r] = -3.0e38f;
    }
    float t0 = fmaxf(fmaxf(s[0][0], s[0][1]), fmaxf(s[0][2], s[0][3]));
    float t1 = fmaxf(fmaxf(s[1][0], s[1][1]), fmaxf(s[1][2], s[1][3]));
    float t2 = fmaxf(fmaxf(s[2][0], s[2][1]), fmaxf(s[2][2], s[2][3]));
    float t3 = fmaxf(fmaxf(s[3][0], s[3][1]), fmaxf(s[3][2], s[3][3]));
    float pmx = fmaxf(fmaxf(t0, t1), fmaxf(t2, t3));
    pmx = fmaxf(pmx, __shfl_xor(pmx, 16));
    pmx = fmaxf(pmx, __shfl_xor(pmx, 32));

    if (!__all(pmx <= mq)) {
      float mn = fmaxf(mq, pmx);
      float alpha = exp2_hw(mq - mn);
      mq = mn;
      lsq *= alpha;
      float alphaT[4];
#pragma unroll
      for (int r = 0; r < 4; ++r)
        alphaT[r] = __shfl(alpha, lhi * 4 + r);
#pragma unroll
      for (int f = 0; f < 4; ++f)
#pragma unroll
        for (int r = 0; r < 4; ++r)
          o[f][r] *= alphaT[r];
    }

    float ps = 0.0f;
#pragma unroll
    for (int n = 0; n < 4; ++n)
#pragma unroll
      for (int r = 0; r < 4; ++r) {
        float pv = exp2_hw(s[n][r] - mq);
        s[n][r] = pv;
        ps += pv;
      }
    ps += __shfl_xor(ps, 16);
    ps += __shfl_xor(ps, 32);
    lsq += ps;

#pragma unroll
    for (int n = 0; n < 4; ++n) {
      uint32_t w0 = cvtpk(s[n][0], s[n][1]);
      uint32_t w1 = cvtpk(s[n][2], s[n][3]);
      int kvloc = n*16 + lhi*4;
      *(uint32_t*)(pbase + ((l16*128 + kvloc*2) ^ swz))       = w0;
      *(uint32_t*)(pbase + ((l16*128 + (kvloc+2)*2) ^ swz))   = w1;
    }
    bf16x8 pa0 = *(const bf16x8*)(pbase + ((l16*128 + 0*64 + lhi*16) ^ swz));
    bf16x8 pa1 = *(const bf16x8*)(pbase + ((l16*128 + 1*64 + lhi*16) ^ swz));

#pragma unroll
    for (int f = 0; f < 4; ++f) {
      const int dr = f * 16 + l16;
      bf16x8 vf0 = *(const bf16x8*)(vc_ + dr*128 + ((lhi     ^ (dr&7)) * 16));
      bf16x8 vf1 = *(const bf16x8*)(vc_ + dr*128 + (((4+lhi) ^ (dr&7)) * 16));
      o[f] = __builtin_amdgcn_mfma_f32_16x16x32_bf16(pa0, vf0, o[f], 0, 0, 0);
      o[f] = __builtin_amdgcn_mfma_f32_16x16x32_bf16(pa1, vf1, o[f], 0, 0, 0);
    }
  };

  /* depth-2 prologue: tiles 0 and 1 in flight (qtB >= 16 so both exist) */
  STAGE(0, 0);
  STAGE(1, 1);

  for (int kt = 0; kt <= qtB; ++kt) {
    if (kt < qtB) asm volatile("s_waitcnt vmcnt(4)" ::: "memory");
    else          asm volatile("s_waitcnt vmcnt(0)" ::: "memory");
    __builtin_amdgcn_s_barrier();
    __builtin_amdgcn_sched_barrier(0);

    if (kt + 2 <= qtB) STAGE((kt + 2) % 3, kt + 2);

    const char* kc_ = (const char*)&Kbuf[kt % 3][0];
    const char* vc_ = (const char*)&Vbuf[kt % 3][0];
    BODY(kc_, vc_, qfB, mqB, lsB, oB, r0B, qtB, kt);
    if (kt <= qtA)
      BODY(kc_, vc_, qfA, mqA, lsA, oA, r0A, qtA, kt);

    __builtin_amdgcn_sched_barrier(0);
  }

  /* epilogue: direct normalized store */
  const int b = bh >> 4, h = bh & 15;
  float invA = 1.0f / lsA, invB = 1.0f / lsB;
#pragma unroll
  for (int r = 0; r < 4; ++r) {
    float wA = __shfl(invA, lhi * 4 + r);
    float wB = __shfl(invB, lhi * 4 + r);
    size_t baseA = ((size_t)(b * SEQ + r0A + lhi*4 + r)) * DMODEL + h * HDIM + l16;
    size_t baseB = ((size_t)(b * SEQ + r0B + lhi*4 + r)) * DMODEL + h * HDIM + l16;
#pragma unroll
    for (int f = 0; f < 4; ++f) {
      ao[baseA + f*16] = f2b(oA[f][r] * wA);
      ao[baseB + f*16] = f2b(oB[f][r] * wB);
    }
  }
}

extern "C" void kernel_launch(void* const* d_in, const int* in_sizes, int n_in,
                              void* d_out, int out_size, void* d_ws, size_t ws_size,
                              hipStream_t stream) {
  const float* x    = (const float*)d_in[0];
  const float* wkqv = (const float*)d_in[1];
  const float* wo   = (const float*)d_in[2];
  float* out = (float*)d_out;

  ushort* xb   = (ushort*)d_ws;                     /* 4096*1024 — reused as attn out */
  ushort* wkb  = xb  + (size_t)MROWS * DMODEL;      /* 3072*1024 */
  ushort* wob  = wkb + (size_t)N3 * DMODEL;         /* 1024*1024 */
  ushort* kqv  = wob + (size_t)DMODEL * DMODEL;     /* 4096*3072 */
  ushort* qb   = kqv + (size_t)MROWS * N3;          /* 4096*1024 */
  ushort* kb   = qb  + (size_t)MROWS * DMODEL;      /* 4096*1024 */
  ushort* vt   = kb  + (size_t)MROWS * DMODEL;      /* 4096*1024 */
  ushort* attn = xb;  /* alias: xb dead after GEMM1 */

  int nx = MROWS * DMODEL / 4, nw = N3 * DMODEL / 4, no = DMODEL * DMODEL / 4;
  f2b3_kernel<<<(nx + nw + no) / 256, 256, 0, stream>>>(x, wkqv, wo, xb, wkb, wob, nx, nw, no);

  gemm_bt<0><<<(MROWS/128) * (N3/128), 256, 0, stream>>>(xb, wkb, (void*)kqv, MROWS, N3, DMODEL);

  prep_kernel<<<1024 + (MROWS * NHEADS * 32) / 256, 256, 0, stream>>>(kqv, qb, kb, vt);

  attn_kernel<<<512, 256, 0, stream>>>(qb, kb, vt, attn);

  gemm_bt<1><<<(MROWS/128) * (DMODEL/128), 256, 0, stream>>>(attn, wob, (void*)out, MROWS, DMODEL, DMODEL);
}

// Round 19
// 119.789 us; speedup vs baseline: 1.1363x; 1.1363x over previous
//
#include <hip/hip_runtime.h>
#include <hip/hip_bf16.h>
#include <stdint.h>

#define BATCH 2
#define SEQ 2048
#define DMODEL 1024
#define NHEADS 16
#define HDIM 64
#define MROWS (BATCH*SEQ)   /* 4096 */
#define N3 (3*DMODEL)       /* 3072 */

typedef __attribute__((ext_vector_type(8))) __bf16 bf16x8;
typedef __attribute__((ext_vector_type(4))) float f32x4;

__device__ __forceinline__ ushort f2b(float f) {
  uint32_t u = __builtin_bit_cast(uint32_t, f);
  uint32_t r = (u + 0x7FFFu + ((u >> 16) & 1u)) >> 16;
  return (ushort)r;
}
__device__ __forceinline__ float b2f(ushort h) {
  return __builtin_bit_cast(float, (uint32_t)h << 16);
}
__device__ __forceinline__ float exp2_hw(float x) {
  float r;
  asm("v_exp_f32 %0, %1" : "=v"(r) : "v"(x));
  return r;
}
/* v_cvt_pk_bf16_f32: d.lo = bf16_rne(a), d.hi = bf16_rne(b) */
__device__ __forceinline__ uint32_t cvtpk(float a, float b) {
  uint32_t r;
  asm("v_cvt_pk_bf16_f32 %0, %1, %2" : "=v"(r) : "v"(a), "v"(b));
  return r;
}

/* ---------------- fused f32 -> bf16 convert, 8 floats/thread (2x float4 -> uint4) ---------------- */
__global__ void f2b3_kernel(const float* __restrict__ a, const float* __restrict__ b,
                            const float* __restrict__ c,
                            ushort* __restrict__ oa, ushort* __restrict__ ob,
                            ushort* __restrict__ oc, int na, int nb, int nc) {
  int i = blockIdx.x * blockDim.x + threadIdx.x;   /* 8-float group index */
  const float* src; ushort* dst; int off;
  if (i < na)           { src = a; dst = oa; off = i; }
  else if (i < na + nb) { src = b; dst = ob; off = i - na; }
  else if (i < na + nb + nc) { src = c; dst = oc; off = i - na - nb; }
  else return;
  float4 v0 = ((const float4*)src)[2*off];
  float4 v1 = ((const float4*)src)[2*off + 1];
  uint4 o;
  o.x = cvtpk(v0.x, v0.y); o.y = cvtpk(v0.z, v0.w);
  o.z = cvtpk(v1.x, v1.y); o.w = cvtpk(v1.z, v1.w);
  ((uint4*)dst)[off] = o;
}

/* ---------------- NT GEMM: C[M,N] = A[M,K] * Bw[N,K]^T  — BK=64 + T2 involution swizzle ----------------
   R16-verified (best total 120.1us): BK=64 halves iterations/barriers vs m97; the
   R15-measured 16-way conflict (row stride 128B = bank period) is fixed by the
   both-sides involution (rule #21): stage source chunk sl = c8 ^ (row&7) with linear
   LDS dest; fragment reads use chunk (kk*4+lhi) ^ (l16&7). R17/R18 proved deeper
   source-level pipelining of this structure is neutral-to-negative — kept 2-barrier. */
template<int OUTF>
__global__ __launch_bounds__(256)
void gemm_bt(const ushort* __restrict__ A, const ushort* __restrict__ Bw,
             void* __restrict__ Cv, int M, int N, int K) {
  __shared__ __align__(16) ushort As[128*64];
  __shared__ __align__(16) ushort Bs[128*64];
  const int tid  = threadIdx.x;
  const int wid  = tid >> 6;
  const int lane = tid & 63;
  const int wr   = wid >> 1, wc = wid & 1;
  const int l16  = lane & 15, lhi = lane >> 4;
  const int nb   = N >> 7;
  const int brow = (blockIdx.x / nb) << 7;
  const int bcol = (blockIdx.x % nb) << 7;

  f32x4 acc[4][4] = {};

  for (int k0 = 0; k0 < K; k0 += 64) {
    __syncthreads();   /* protect LDS from previous iteration's readers */
#pragma unroll
    for (int it = 0; it < 4; ++it) {
      const int cb = (wid * 4 + it) * 64;      /* wave-uniform chunk base */
      const int ci = cb + lane;
      const int r  = ci >> 3;                  /* 8 chunks per 64-elem row */
      const int sl = (ci & 7) ^ (r & 7);       /* pre-swizzled source chunk */
      const ushort* ga = A  + (size_t)(brow + r) * K + k0 + sl * 8;
      const ushort* gb = Bw + (size_t)(bcol + r) * K + k0 + sl * 8;
      __builtin_amdgcn_global_load_lds(
          (const __attribute__((address_space(1))) void*)ga,
          (__attribute__((address_space(3))) void*)(As + cb * 8), 16, 0, 0);
      __builtin_amdgcn_global_load_lds(
          (const __attribute__((address_space(1))) void*)gb,
          (__attribute__((address_space(3))) void*)(Bs + cb * 8), 16, 0, 0);
    }
    __syncthreads();   /* drains vmcnt(0): staged data visible */

#pragma unroll
    for (int kk = 0; kk < 2; ++kk) {
      bf16x8 af[4], bfr[4];
#pragma unroll
      for (int m = 0; m < 4; ++m)
        af[m] = *(const bf16x8*)(As + (wr*64 + m*16 + l16)*64 + (((kk*4+lhi) ^ (l16 & 7)) * 8));
#pragma unroll
      for (int n = 0; n < 4; ++n)
        bfr[n] = *(const bf16x8*)(Bs + (wc*64 + n*16 + l16)*64 + (((kk*4+lhi) ^ (l16 & 7)) * 8));
#pragma unroll
      for (int m = 0; m < 4; ++m)
#pragma unroll
        for (int n = 0; n < 4; ++n)
          acc[m][n] = __builtin_amdgcn_mfma_f32_16x16x32_bf16(af[m], bfr[n], acc[m][n], 0, 0, 0);
    }
  }

#pragma unroll
  for (int m = 0; m < 4; ++m)
#pragma unroll
    for (int n = 0; n < 4; ++n)
#pragma unroll
      for (int r = 0; r < 4; ++r) {
        const int row = brow + wr*64 + m*16 + lhi*4 + r;
        const int col = bcol + wc*64 + n*16 + l16;
        if (OUTF) ((float*)Cv)[(size_t)row * N + col] = acc[m][n][r];
        else      ((ushort*)Cv)[(size_t)row * N + col] = f2b(acc[m][n][r]);
      }
}

/* ---------------- prep: fused V-transpose (blocks 0..1023) + RoPE (blocks 1024..9215) ---------------- */
__global__ __launch_bounds__(256)
void prep_kernel(const ushort* __restrict__ kqv,
                 ushort* __restrict__ qb, ushort* __restrict__ kb, ushort* __restrict__ vt) {
  __shared__ ushort tile[64][65];
  if (blockIdx.x < 1024) {
    int bid = blockIdx.x;
    int lt = bid & 31, bh = bid >> 5;
    int b = bh >> 4, h = bh & 15;
    int tid = threadIdx.x;
    int r = tid >> 2, cq = tid & 3;
    size_t gbase = ((size_t)(b * SEQ + lt * 64 + r)) * N3 + 2 * DMODEL + h * HDIM + cq * 16;
#pragma unroll
    for (int j = 0; j < 16; ++j) tile[r][cq * 16 + j] = kqv[gbase + j];
    __syncthreads();
    int d = tid >> 2;
    size_t obase = ((size_t)(bh * HDIM + d)) * SEQ + lt * 64 + cq * 16;
#pragma unroll
    for (int j = 0; j < 16; ++j) vt[obase + j] = tile[cq * 16 + j][d];
  } else {
    const float SC = 0.18033688011112042f;  /* 0.125 * log2(e) */
    int idx = (blockIdx.x - 1024) * 256 + threadIdx.x;
    int i  = idx & 31;
    int h  = (idx >> 5) & 15;
    int bl = idx >> 9;
    int l  = bl & (SEQ - 1);
    int b  = bl >> 11;
    float inv = exp2f((float)i * -0.4152410118609203f);  /* 10000^(-i/32) */
    float ang = (float)l * inv;
    float s, c;
    sincosf(ang, &s, &c);
    size_t base = (size_t)bl * N3 + h * HDIM + 2 * i;
    uint32_t kp = *(const uint32_t*)(kqv + base);
    uint32_t qp = *(const uint32_t*)(kqv + base + DMODEL);
    float k1 = b2f((ushort)(kp & 0xffff)), k2 = b2f((ushort)(kp >> 16));
    float q1 = b2f((ushort)(qp & 0xffff)), q2 = b2f((ushort)(qp >> 16));
    float kr1 = k1 * c - k2 * s, kr2 = k1 * s + k2 * c;
    float qr1 = (q1 * c - q2 * s) * SC, qr2 = (q1 * s + q2 * c) * SC;
    size_t ob = ((size_t)(b * NHEADS + h) * SEQ + l) * HDIM + 2 * i;
    *(uint32_t*)(kb + ob) = cvtpk(kr1, kr2);
    *(uint32_t*)(qb + ob) = cvtpk(qr1, qr2);
  }
}

/* ---------------- Flash attention (R10 verified, 45.6us): folded pair, counted-vmcnt ---------------- */
__global__ __launch_bounds__(256, 2)
void attn_kernel(const ushort* __restrict__ qb, const ushort* __restrict__ kb,
                 const ushort* __restrict__ vt, ushort* __restrict__ ao) {
  __shared__ __align__(16) ushort Kbuf[3][4096];   /* [kv 64][d 64] swizzled */
  __shared__ __align__(16) ushort Vbuf[3][4096];   /* [d 64][kv 64] swizzled */
  __shared__ __align__(16) ushort plds[4][1024];   /* per-wave P bounce */
  const int bid = blockIdx.x;
  const int bh = bid & 31;
  const int p  = bid >> 5;           /* 0..15 */
  const int qtA = p, qtB = 31 - p;   /* qtB >= qtA >= 0; qtB >= 16 */

  const int wid = threadIdx.x >> 6, lane = threadIdx.x & 63;
  const int l16 = lane & 15, lhi = lane >> 4;
  const int r0A = qtA * 64 + wid * 16;
  const int r0B = qtB * 64 + wid * 16;

  const ushort* Q  = qb + (size_t)bh * SEQ * HDIM;
  const ushort* Kp = kb + (size_t)bh * SEQ * HDIM;
  const ushort* Vp = vt + (size_t)bh * HDIM * SEQ;

  bf16x8 qfA[2], qfB[2];
#pragma unroll
  for (int kc = 0; kc < 2; ++kc) {
    qfA[kc] = *(const bf16x8*)(Q + (size_t)(r0A + l16) * HDIM + kc * 32 + lhi * 8);
    qfB[kc] = *(const bf16x8*)(Q + (size_t)(r0B + l16) * HDIM + kc * 32 + lhi * 8);
  }

  float mqA = -3.0e38f, lsA = 0.0f, mqB = -3.0e38f, lsB = 0.0f;
  f32x4 oA[4] = {}, oB[4] = {};

  char* pbase = (char*)&plds[wid][0];
  const int swz = (l16 & 7) << 4;

  auto STAGE = [&](int buf, int kt) {
    ushort* kd = &Kbuf[buf][0];
    ushort* vd = &Vbuf[buf][0];
    const ushort* kg = Kp + (size_t)kt * 64 * HDIM;
    const ushort* vg = Vp + kt * 64;
#pragma unroll
    for (int it = 0; it < 2; ++it) {
      const int cb = it * 256 + wid * 64;
      const int ci = cb + lane;
      const int row = ci >> 3;
      const int sl  = (ci & 7) ^ (row & 7);
      __builtin_amdgcn_global_load_lds(
          (const __attribute__((address_space(1))) void*)(kg + row * HDIM + sl * 8),
          (__attribute__((address_space(3))) void*)(kd + cb * 8), 16, 0, 0);
      __builtin_amdgcn_global_load_lds(
          (const __attribute__((address_space(1))) void*)(vg + (size_t)row * SEQ + sl * 8),
          (__attribute__((address_space(3))) void*)(vd + cb * 8), 16, 0, 0);
    }
  };

  auto BODY = [&](const char* kc_, const char* vc_, bf16x8 (&qf)[2],
                  float& mq, float& lsq, f32x4 (&o)[4], int r0, int qt, int kt) {
    f32x4 s[4];
#pragma unroll
    for (int n = 0; n < 4; ++n) {
      const int kvr = n * 16 + l16;
      bf16x8 kf0 = *(const bf16x8*)(kc_ + kvr*128 + ((lhi     ^ (kvr&7)) * 16));
      bf16x8 kf1 = *(const bf16x8*)(kc_ + kvr*128 + (((4+lhi) ^ (kvr&7)) * 16));
      f32x4 z = 0.0f;
      z = __builtin_amdgcn_mfma_f32_16x16x32_bf16(kf0, qf[0], z, 0, 0, 0);
      z = __builtin_amdgcn_mfma_f32_16x16x32_bf16(kf1, qf[1], z, 0, 0, 0);
      s[n] = z;
    }
    if (kt == qt) {
#pragma unroll
      for (int n = 0; n < 4; ++n)
#pragma unroll
        for (int r = 0; r < 4; ++r)
          if (kt*64 + n*16 + lhi*4 + r > r0 + l16) s[n][r] = -3.0e38f;
    }
    float t0 = fmaxf(fmaxf(s[0][0], s[0][1]), fmaxf(s[0][2], s[0][3]));
    float t1 = fmaxf(fmaxf(s[1][0], s[1][1]), fmaxf(s[1][2], s[1][3]));
    float t2 = fmaxf(fmaxf(s[2][0], s[2][1]), fmaxf(s[2][2], s[2][3]));
    float t3 = fmaxf(fmaxf(s[3][0], s[3][1]), fmaxf(s[3][2], s[3][3]));
    float pmx = fmaxf(fmaxf(t0, t1), fmaxf(t2, t3));
    pmx = fmaxf(pmx, __shfl_xor(pmx, 16));
    pmx = fmaxf(pmx, __shfl_xor(pmx, 32));

    if (!__all(pmx <= mq)) {
      float mn = fmaxf(mq, pmx);
      float alpha = exp2_hw(mq - mn);
      mq = mn;
      lsq *= alpha;
      float alphaT[4];
#pragma unroll
      for (int r = 0; r < 4; ++r)
        alphaT[r] = __shfl(alpha, lhi * 4 + r);
#pragma unroll
      for (int f = 0; f < 4; ++f)
#pragma unroll
        for (int r = 0; r < 4; ++r)
          o[f][r] *= alphaT[r];
    }

    float ps = 0.0f;
#pragma unroll
    for (int n = 0; n < 4; ++n)
#pragma unroll
      for (int r = 0; r < 4; ++r) {
        float pv = exp2_hw(s[n][r] - mq);
        s[n][r] = pv;
        ps += pv;
      }
    ps += __shfl_xor(ps, 16);
    ps += __shfl_xor(ps, 32);
    lsq += ps;

#pragma unroll
    for (int n = 0; n < 4; ++n) {
      uint32_t w0 = cvtpk(s[n][0], s[n][1]);
      uint32_t w1 = cvtpk(s[n][2], s[n][3]);
      int kvloc = n*16 + lhi*4;
      *(uint32_t*)(pbase + ((l16*128 + kvloc*2) ^ swz))       = w0;
      *(uint32_t*)(pbase + ((l16*128 + (kvloc+2)*2) ^ swz))   = w1;
    }
    bf16x8 pa0 = *(const bf16x8*)(pbase + ((l16*128 + 0*64 + lhi*16) ^ swz));
    bf16x8 pa1 = *(const bf16x8*)(pbase + ((l16*128 + 1*64 + lhi*16) ^ swz));

#pragma unroll
    for (int f = 0; f < 4; ++f) {
      const int dr = f * 16 + l16;
      bf16x8 vf0 = *(const bf16x8*)(vc_ + dr*128 + ((lhi     ^ (dr&7)) * 16));
      bf16x8 vf1 = *(const bf16x8*)(vc_ + dr*128 + (((4+lhi) ^ (dr&7)) * 16));
      o[f] = __builtin_amdgcn_mfma_f32_16x16x32_bf16(pa0, vf0, o[f], 0, 0, 0);
      o[f] = __builtin_amdgcn_mfma_f32_16x16x32_bf16(pa1, vf1, o[f], 0, 0, 0);
    }
  };

  /* depth-2 prologue: tiles 0 and 1 in flight (qtB >= 16 so both exist) */
  STAGE(0, 0);
  STAGE(1, 1);

  for (int kt = 0; kt <= qtB; ++kt) {
    if (kt < qtB) asm volatile("s_waitcnt vmcnt(4)" ::: "memory");
    else          asm volatile("s_waitcnt vmcnt(0)" ::: "memory");
    __builtin_amdgcn_s_barrier();
    __builtin_amdgcn_sched_barrier(0);

    if (kt + 2 <= qtB) STAGE((kt + 2) % 3, kt + 2);

    const char* kc_ = (const char*)&Kbuf[kt % 3][0];
    const char* vc_ = (const char*)&Vbuf[kt % 3][0];
    BODY(kc_, vc_, qfB, mqB, lsB, oB, r0B, qtB, kt);
    if (kt <= qtA)
      BODY(kc_, vc_, qfA, mqA, lsA, oA, r0A, qtA, kt);

    __builtin_amdgcn_sched_barrier(0);
  }

  /* epilogue: direct normalized store */
  const int b = bh >> 4, h = bh & 15;
  float invA = 1.0f / lsA, invB = 1.0f / lsB;
#pragma unroll
  for (int r = 0; r < 4; ++r) {
    float wA = __shfl(invA, lhi * 4 + r);
    float wB = __shfl(invB, lhi * 4 + r);
    size_t baseA = ((size_t)(b * SEQ + r0A + lhi*4 + r)) * DMODEL + h * HDIM + l16;
    size_t baseB = ((size_t)(b * SEQ + r0B + lhi*4 + r)) * DMODEL + h * HDIM + l16;
#pragma unroll
    for (int f = 0; f < 4; ++f) {
      ao[baseA + f*16] = f2b(oA[f][r] * wA);
      ao[baseB + f*16] = f2b(oB[f][r] * wB);
    }
  }
}

extern "C" void kernel_launch(void* const* d_in, const int* in_sizes, int n_in,
                              void* d_out, int out_size, void* d_ws, size_t ws_size,
                              hipStream_t stream) {
  const float* x    = (const float*)d_in[0];
  const float* wkqv = (const float*)d_in[1];
  const float* wo   = (const float*)d_in[2];
  float* out = (float*)d_out;

  ushort* xb   = (ushort*)d_ws;                     /* 4096*1024 — reused as attn out */
  ushort* wkb  = xb  + (size_t)MROWS * DMODEL;      /* 3072*1024 */
  ushort* wob  = wkb + (size_t)N3 * DMODEL;         /* 1024*1024 */
  ushort* kqv  = wob + (size_t)DMODEL * DMODEL;     /* 4096*3072 */
  ushort* qb   = kqv + (size_t)MROWS * N3;          /* 4096*1024 */
  ushort* kb   = qb  + (size_t)MROWS * DMODEL;      /* 4096*1024 */
  ushort* vt   = kb  + (size_t)MROWS * DMODEL;      /* 4096*1024 */
  ushort* attn = xb;  /* alias: xb dead after GEMM1 */

  /* 8-float groups per buffer */
  int nx = MROWS * DMODEL / 8, nw = N3 * DMODEL / 8, no = DMODEL * DMODEL / 8;
  f2b3_kernel<<<(nx + nw + no) / 256, 256, 0, stream>>>(x, wkqv, wo, xb, wkb, wob, nx, nw, no);

  gemm_bt<0><<<(MROWS/128) * (N3/128), 256, 0, stream>>>(xb, wkb, (void*)kqv, MROWS, N3, DMODEL);

  prep_kernel<<<1024 + (MROWS * NHEADS * 32) / 256, 256, 0, stream>>>(kqv, qb, kb, vt);

  attn_kernel<<<512, 256, 0, stream>>>(qb, kb, vt, attn);

  gemm_bt<1><<<(MROWS/128) * (DMODEL/128), 256, 0, stream>>>(attn, wob, (void*)out, MROWS, DMODEL, DMODEL);
}